// Round 4
// baseline (560.451 us; speedup 1.0000x reference)
//
#include <hip/hip_runtime.h>
#include <hip/hip_bf16.h>

#define H 512
#define B 64
#define S 2048

typedef __bf16 bf16x8 __attribute__((ext_vector_type(8)));
typedef float f32x4 __attribute__((ext_vector_type(4)));

// pack two fp32 -> two bf16 (RNE) in one uint (low = x)
__device__ __forceinline__ unsigned cvt2(float x, float y) {
    union { __hip_bfloat162 h; unsigned u; } cv;
    cv.h = __float22bfloat162_rn(make_float2(x, y));
    return cv.u;
}

__device__ __forceinline__ float fast_tanh(float x) {
    float e = __expf(2.0f * x);
    float r = __builtin_amdgcn_rcpf(e + 1.0f);
    return 1.0f - 2.0f * r;
}

// async 16B global -> LDS (wave-uniform LDS base + lane*16; global addr per-lane)
__device__ __forceinline__ void gload_lds16(const void* g, void* l) {
    __builtin_amdgcn_global_load_lds(
        (const __attribute__((address_space(1))) unsigned int*)g,
        (__attribute__((address_space(3))) unsigned int*)l, 16, 0, 0);
}

// W_w fp32 -> bf16 once
__global__ __launch_bounds__(256) void w16_kernel(const float* __restrict__ Ww,
                                                  unsigned short* __restrict__ w16) {
    const int i = (blockIdx.x * 256 + threadIdx.x) * 8;
    float4 a = *(const float4*)(Ww + i);
    float4 b = *(const float4*)(Ww + i + 4);
    uint4 p;
    p.x = cvt2(a.x, a.y); p.y = cvt2(a.z, a.w);
    p.z = cvt2(b.x, b.y); p.w = cvt2(b.z, b.w);
    *(uint4*)(w16 + i) = p;
}

// u[b,k] = U_b[k] + W_b[k] + sum_h U_w[k,h] * hid[b,h]
__global__ __launch_bounds__(256) void u_kernel(
        const float* __restrict__ hid, const float* __restrict__ Uw,
        const float* __restrict__ Ub, const float* __restrict__ Wb,
        float* __restrict__ u) {
    const int b = blockIdx.y;
    const int k = blockIdx.x * 4 + (threadIdx.x >> 6);
    const int lane = threadIdx.x & 63;
    const float4* wrow = (const float4*)(Uw + (size_t)k * H);
    const float4* hrow = (const float4*)(hid + (size_t)b * H);
    float4 w0 = wrow[lane * 2], w1 = wrow[lane * 2 + 1];
    float4 h0 = hrow[lane * 2], h1 = hrow[lane * 2 + 1];
    float acc = w0.x * h0.x + w0.y * h0.y + w0.z * h0.z + w0.w * h0.w
              + w1.x * h1.x + w1.y * h1.y + w1.z * h1.z + w1.w * h1.w;
    #pragma unroll
    for (int off = 1; off < 64; off <<= 1) acc += __shfl_xor(acc, off, 64);
    if (lane == 0) u[b * H + k] = acc + Ub[k] + Wb[k];
}

// ---------------------------------------------------------------------------
// energy: classic m97-style 2-barrier GEMM tile. 256 thr / 4 waves (2x2),
// wave owns 64x64, acc[4][4] (64 VGPR — normal GEMM pressure, no giant
// persistent array for the allocator to spill).
// nt-loop x4 over W cols (A re-read from L3); kt-loop x16 (BK=32).
// A (enc fp32): reg-staged, cvt2, ds_write into PADDED As[128][40] (80B rows
//   -> ds_read_b128 start slots uniform 8-per-128B = conflict-free).
// B (w16 bf16): global_load_lds direct, 16B-chunk XOR swizzle (slot ^= row&3)
//   applied on the pre-swizzled GLOBAL source (LDS dest linear) = conflict-free.
// Epilogue per nt: esum[i][r] += v[col]*tanh(u[col]+acc) — C never stored.
// ---------------------------------------------------------------------------
__global__ __launch_bounds__(256, 3) void energy_kernel(
        const float* __restrict__ enc, const unsigned short* __restrict__ w16,
        const float* __restrict__ Vw, const float* __restrict__ u,
        float* __restrict__ energy) {
    const int s0  = blockIdx.x * 128;
    const int b   = blockIdx.y;
    const int tid = threadIdx.x;
    const int wave = tid >> 6, lane = tid & 63;
    const int quad = lane >> 4, c = lane & 15;
    const int wr = wave >> 1, wc = wave & 1;

    __shared__ unsigned short As[128][40];      // 10 KB, padded 80B rows
    __shared__ unsigned char  Bsh[2][8192];     // 16 KB, [128 cols][64B], swizzled
    __shared__ float uS[H], vS[H];              // 4 KB
    __shared__ float red[128];                  // 0.5 KB

    const int brow_l = lane >> 2;               // row within 16-row lgds group
    const int bcs    = lane & 3;                // dest 16B chunk slot

    const unsigned char* wb = (const unsigned char*)w16;

    // B-tile staging: 2 lgds per wave, 16 rows x 64B each, source chunk-swizzled
    #define STAGE_B(nt, kt, buf)                                               \
        _Pragma("unroll")                                                      \
        for (int i_ = 0; i_ < 2; ++i_) {                                       \
            const int row_ = wave * 32 + i_ * 16 + brow_l;                     \
            gload_lds16(wb + ((size_t)((nt) * 128 + row_) * H + (kt) * 32) * 2 \
                           + ((bcs ^ (row_ & 3)) * 16),                        \
                        &Bsh[buf][(wave * 32 + i_ * 16) * 64]);                \
        }

    const int r  = tid >> 1;                    // A row 0..127
    const int hh = (tid & 1) * 16;              // element offset in 32-col chunk
    const float* pa = enc + ((size_t)(b * S + s0 + r)) * H + hh;

    float4 ar0, ar1, ar2, ar3;
    #define LOAD_A(kt) {                                                       \
        const float* p_ = pa + (kt) * 32;                                      \
        ar0 = *(const float4*)(p_);                                            \
        ar1 = *(const float4*)(p_ + 4);                                        \
        ar2 = *(const float4*)(p_ + 8);                                        \
        ar3 = *(const float4*)(p_ + 12);                                       \
    }

    // prologue: B(0,0) into buf 0 (oldest in FIFO), A(kt=0) into regs
    STAGE_B(0, 0, 0);
    LOAD_A(0);
    for (int i = tid; i < H; i += 256) { uS[i] = u[b * H + i]; vS[i] = Vw[i]; }

    float esum[4][4] = {};
    const f32x4 fzero = {0.f, 0.f, 0.f, 0.f};

    for (int nt = 0; nt < 4; ++nt) {
        f32x4 acc[4][4];
        #pragma unroll
        for (int i = 0; i < 4; ++i)
            #pragma unroll
            for (int j = 0; j < 4; ++j) acc[i][j] = fzero;

        for (int kt = 0; kt < 16; ++kt) {
            const int buf = kt & 1;
            __syncthreads();                  // prev readers done; inflight drains
            {   // convert + write A tile (regs loaded last iteration)
                uint4 p0, p1;
                p0.x = cvt2(ar0.x, ar0.y); p0.y = cvt2(ar0.z, ar0.w);
                p0.z = cvt2(ar1.x, ar1.y); p0.w = cvt2(ar1.z, ar1.w);
                p1.x = cvt2(ar2.x, ar2.y); p1.y = cvt2(ar2.z, ar2.w);
                p1.z = cvt2(ar3.x, ar3.y); p1.w = cvt2(ar3.z, ar3.w);
                *(uint4*)&As[r][hh]     = p0;
                *(uint4*)&As[r][hh + 8] = p1;
            }
            __syncthreads();                  // tiles visible
            const int tn = nt * 16 + kt + 1;  // prefetch next step (flies in MFMA)
            if (tn < 64) {
                STAGE_B(tn >> 4, tn & 15, buf ^ 1);
                LOAD_A(tn & 15);
            }
            bf16x8 af[4], bf[4];
            #pragma unroll
            for (int i = 0; i < 4; ++i)
                af[i] = *(const bf16x8*)&As[wr * 64 + i * 16 + c][quad * 8];
            #pragma unroll
            for (int j = 0; j < 4; ++j) {
                const int R = wc * 64 + j * 16 + c;
                bf[j] = *(const bf16x8*)&Bsh[buf][R * 64 + ((quad ^ (c & 3)) * 16)];
            }
            #pragma unroll
            for (int i = 0; i < 4; ++i)
                #pragma unroll
                for (int j = 0; j < 4; ++j)
                    acc[i][j] = __builtin_amdgcn_mfma_f32_16x16x32_bf16(af[i], bf[j], acc[i][j], 0, 0, 0);
        }
        // fold this n-tile into energies
        #pragma unroll
        for (int j = 0; j < 4; ++j) {
            const int col = nt * 128 + wc * 64 + j * 16 + c;
            const float vv = vS[col], uu = uS[col];
            #pragma unroll
            for (int i = 0; i < 4; ++i)
                #pragma unroll
                for (int rr = 0; rr < 4; ++rr)
                    esum[i][rr] += vv * fast_tanh(uu + acc[i][j][rr]);
        }
    }

    // reduce over 16 col-lanes, then combine the two wc-waves via LDS
    #pragma unroll
    for (int i = 0; i < 4; ++i)
        #pragma unroll
        for (int rr = 0; rr < 4; ++rr) {
            float e = esum[i][rr];
            e += __shfl_xor(e, 1, 64);
            e += __shfl_xor(e, 2, 64);
            e += __shfl_xor(e, 4, 64);
            e += __shfl_xor(e, 8, 64);
            esum[i][rr] = e;
        }
    __syncthreads();
    if (wc == 0 && c == 0) {
        #pragma unroll
        for (int i = 0; i < 4; ++i)
            #pragma unroll
            for (int rr = 0; rr < 4; ++rr)
                red[wr * 64 + i * 16 + quad * 4 + rr] = esum[i][rr];
    }
    __syncthreads();
    if (wc == 1 && c == 0) {
        #pragma unroll
        for (int i = 0; i < 4; ++i)
            #pragma unroll
            for (int rr = 0; rr < 4; ++rr) {
                const int row = wr * 64 + i * 16 + quad * 4 + rr;
                energy[b * S + s0 + row] = red[row] + esum[i][rr];
            }
    }
    #undef STAGE_B
    #undef LOAD_A
}

__global__ void softmax_kernel(const float* __restrict__ energy, float* __restrict__ attn) {
    int b = blockIdx.x;
    int t = threadIdx.x;              // 256
    const float* e = energy + b * S;
    float v[8];
    float m = -1e30f;
    #pragma unroll
    for (int i = 0; i < 8; ++i) { v[i] = e[t + i * 256]; m = fmaxf(m, v[i]); }
    #pragma unroll
    for (int off = 1; off < 64; off <<= 1) m = fmaxf(m, __shfl_xor(m, off, 64));
    __shared__ float redm[4], reds[4];
    if ((t & 63) == 0) redm[t >> 6] = m;
    __syncthreads();
    m = fmaxf(fmaxf(redm[0], redm[1]), fmaxf(redm[2], redm[3]));
    float s = 0.f;
    #pragma unroll
    for (int i = 0; i < 8; ++i) { v[i] = __expf(v[i] - m); s += v[i]; }
    #pragma unroll
    for (int off = 1; off < 64; off <<= 1) s += __shfl_xor(s, off, 64);
    if ((t & 63) == 0) reds[t >> 6] = s;
    __syncthreads();
    float inv = 1.0f / (reds[0] + reds[1] + reds[2] + reds[3]);
    #pragma unroll
    for (int i = 0; i < 8; ++i) attn[b * S + t + i * 256] = v[i] * inv;
}

// context: float4 loads (16B/lane), 2 s-groups x 128 h-lanes, LDS combine,
// then one atomicAdd set per block (16 blocks per b).
#define CCH 128
__global__ __launch_bounds__(256) void context_kernel(
        const float* __restrict__ enc, const float* __restrict__ attn,
        float* __restrict__ ctx) {
    const int b  = blockIdx.x >> 4;
    const int ch = blockIdx.x & 15;
    const int t  = threadIdx.x;          // 256
    const int grp = t >> 7;              // 0/1: s-half
    const int ln  = t & 127;             // h-lane (float4)
    __shared__ float aS[CCH];
    __shared__ float red[H];
    if (t < CCH) aS[t] = attn[b * S + ch * CCH + t];
    __syncthreads();
    const float* ebase = enc + ((size_t)(b * S + ch * CCH) + grp * 64) * H + ln * 4;
    float4 acc = make_float4(0.f, 0.f, 0.f, 0.f);
    #pragma unroll 8
    for (int s = 0; s < 64; ++s) {
        const float a = aS[grp * 64 + s];
        const float4 e = *(const float4*)(ebase + (size_t)s * H);
        acc.x += a * e.x; acc.y += a * e.y; acc.z += a * e.z; acc.w += a * e.w;
    }
    if (grp == 0) *(float4*)&red[ln * 4] = acc;
    __syncthreads();
    if (grp == 1) {
        const float4 r = *(const float4*)&red[ln * 4];
        atomicAdd(&ctx[b * H + ln * 4 + 0], acc.x + r.x);
        atomicAdd(&ctx[b * H + ln * 4 + 1], acc.y + r.y);
        atomicAdd(&ctx[b * H + ln * 4 + 2], acc.z + r.z);
        atomicAdd(&ctx[b * H + ln * 4 + 3], acc.w + r.w);
    }
}

extern "C" void kernel_launch(void* const* d_in, const int* in_sizes, int n_in,
                              void* d_out, int out_size, void* d_ws, size_t ws_size,
                              hipStream_t stream) {
    (void)in_sizes; (void)n_in; (void)out_size; (void)ws_size;
    const float* hid = (const float*)d_in[0];
    const float* enc = (const float*)d_in[1];
    const float* Uw  = (const float*)d_in[2];
    const float* Ub  = (const float*)d_in[3];
    const float* Ww  = (const float*)d_in[4];
    const float* Wb  = (const float*)d_in[5];
    const float* Vw  = (const float*)d_in[6];
    // V_b unused: softmax shift-invariant, energy not an output.

    float* out_ctx  = (float*)d_out;          // 64*512
    float* out_attn = out_ctx + B * H;        // 64*2048
    float* energy   = (float*)d_ws;           // 64*2048 fp32
    float* u        = energy + B * S;         // 64*512 fp32
    unsigned short* w16 = (unsigned short*)(u + B * H);   // 512*512 bf16

    hipMemsetAsync(d_out, 0, (size_t)B * H * sizeof(float), stream);   // ctx accum target

    w16_kernel<<<dim3(H * H / (256 * 8)), 256, 0, stream>>>(Ww, w16);
    u_kernel<<<dim3(H / 4, B), 256, 0, stream>>>(hid, Uw, Ub, Wb, u);
    energy_kernel<<<dim3(S / 128, B), 256, 0, stream>>>(enc, w16, Vw, u, energy);
    softmax_kernel<<<B, 256, 0, stream>>>(energy, out_attn);
    context_kernel<<<B * 16, 256, 0, stream>>>(enc, out_attn, out_ctx);
}

// Round 5
// 500.678 us; speedup vs baseline: 1.1194x; 1.1194x over previous
//
#include <hip/hip_runtime.h>
#include <hip/hip_bf16.h>

#define H 512
#define B 64
#define S 2048

typedef __bf16 bf16x8 __attribute__((ext_vector_type(8)));
typedef float f32x4 __attribute__((ext_vector_type(4)));

// pack two fp32 -> two bf16 (RNE) in one uint (low = x)
__device__ __forceinline__ unsigned cvt2(float x, float y) {
    union { __hip_bfloat162 h; unsigned u; } cv;
    cv.h = __float22bfloat162_rn(make_float2(x, y));
    return cv.u;
}

__device__ __forceinline__ float fast_tanh(float x) {
    float e = __expf(2.0f * x);
    float r = __builtin_amdgcn_rcpf(e + 1.0f);
    return 1.0f - 2.0f * r;
}

// W_w fp32 -> bf16 once (B operand source, stays L2-resident: 512 KB)
__global__ __launch_bounds__(256) void w16_kernel(const float* __restrict__ Ww,
                                                  unsigned short* __restrict__ w16) {
    const int i = (blockIdx.x * 256 + threadIdx.x) * 8;
    float4 a = *(const float4*)(Ww + i);
    float4 b = *(const float4*)(Ww + i + 4);
    uint4 p;
    p.x = cvt2(a.x, a.y); p.y = cvt2(a.z, a.w);
    p.z = cvt2(b.x, b.y); p.w = cvt2(b.z, b.w);
    *(uint4*)(w16 + i) = p;
}

// u[b,k] = U_b[k] + W_b[k] + sum_h U_w[k,h] * hid[b,h]
__global__ __launch_bounds__(256) void u_kernel(
        const float* __restrict__ hid, const float* __restrict__ Uw,
        const float* __restrict__ Ub, const float* __restrict__ Wb,
        float* __restrict__ u) {
    const int b = blockIdx.y;
    const int k = blockIdx.x * 4 + (threadIdx.x >> 6);
    const int lane = threadIdx.x & 63;
    const float4* wrow = (const float4*)(Uw + (size_t)k * H);
    const float4* hrow = (const float4*)(hid + (size_t)b * H);
    float4 w0 = wrow[lane * 2], w1 = wrow[lane * 2 + 1];
    float4 h0 = hrow[lane * 2], h1 = hrow[lane * 2 + 1];
    float acc = w0.x * h0.x + w0.y * h0.y + w0.z * h0.z + w0.w * h0.w
              + w1.x * h1.x + w1.y * h1.y + w1.z * h1.z + w1.w * h1.w;
    #pragma unroll
    for (int off = 1; off < 64; off <<= 1) acc += __shfl_xor(acc, off, 64);
    if (lane == 0) u[b * H + k] = acc + Ub[k] + Wb[k];
}

// ---------------------------------------------------------------------------
// energy: BM=64, 512 thr / 8 waves, wave owns 64x64 output (4x4 frags, the
// LDS:MFMA-balanced tile). A = enc[64][512] bf16 in LDS, loaded from HBM
// EXACTLY ONCE per block (enc total traffic = 256 MB, vs 529 MB in round 4),
// staged in 4 software-pipelined phases (load slice p+1 || compute slice p).
// B (w16, [col][h], 512 KB, L2-resident) is read DIRECTLY from global as
// per-lane bf16x8 fragments — no LDS at all for B. LDS = 70 KB -> 2 blocks/CU,
// so one block's A-load phase overlaps the other's MFMA phase.
// A chunk-XOR swizzle: 16B chunk index ^= (row&7), write + read side.
// ---------------------------------------------------------------------------
__global__ __launch_bounds__(512, 4) void energy_kernel(
        const float* __restrict__ enc, const unsigned short* __restrict__ w16,
        const float* __restrict__ Vw, const float* __restrict__ u,
        float* __restrict__ energy) {
    const int s0  = blockIdx.x * 64;
    const int b   = blockIdx.y;
    const int tid = threadIdx.x;          // 0..511
    const int wave = tid >> 6, lane = tid & 63;
    const int quad = lane >> 4, c = lane & 15;

    __shared__ unsigned short As[64][512];    // 64 KB, chunk-swizzled
    __shared__ float uS[H], vS[H];            // 4 KB
    __shared__ float red[8][64];              // 2 KB

    // A staging: thread owns row (tid>>3), 16 floats per phase at (tid&7)*16
    const int arow = tid >> 3;
    const int a8   = tid & 7;
    const int akey = arow & 7;
    const float* pa = enc + ((size_t)(b * S + s0 + arow)) * H + a8 * 16;
    unsigned char* arowbase = (unsigned char*)&As[arow][0];

    float4 av0, av1, av2, av3;
#define ALOAD(p) { const float4* q_ = (const float4*)(pa + (p) * 128);         \
    av0 = q_[0]; av1 = q_[1]; av2 = q_[2]; av3 = q_[3]; }
#define AWRITE(p) { uint4 lo_, hi_;                                            \
    lo_.x = cvt2(av0.x, av0.y); lo_.y = cvt2(av0.z, av0.w);                    \
    lo_.z = cvt2(av1.x, av1.y); lo_.w = cvt2(av1.z, av1.w);                    \
    hi_.x = cvt2(av2.x, av2.y); hi_.y = cvt2(av2.z, av2.w);                    \
    hi_.z = cvt2(av3.x, av3.y); hi_.w = cvt2(av3.z, av3.w);                    \
    const int ci_ = (p) * 16 + a8 * 2;                                         \
    *(uint4*)(arowbase + (((ci_)     ^ akey) << 4)) = lo_;                     \
    *(uint4*)(arowbase + (((ci_ + 1) ^ akey) << 4)) = hi_; }

    ALOAD(0);
    uS[tid] = u[b * H + tid];
    vS[tid] = Vw[tid];
    AWRITE(0);
    __syncthreads();

    const f32x4 fzero = {0.f, 0.f, 0.f, 0.f};
    f32x4 acc[4][4];
    #pragma unroll
    for (int i = 0; i < 4; ++i)
        #pragma unroll
        for (int j = 0; j < 4; ++j) acc[i][j] = fzero;

    // per-lane B base: col = wave*64 + j*16 + c, h-elems quad*8..+7
    const unsigned short* wbase = w16 + (size_t)(wave * 64 + c) * H + quad * 8;

    #pragma unroll
    for (int p = 0; p < 4; ++p) {
        if (p < 3) ALOAD(p + 1);          // next A slice flies under MFMA
        #pragma unroll
        for (int k2 = 0; k2 < 4; ++k2) {
            const int kt = p * 4 + k2;
            bf16x8 bf[4], af[4];
            #pragma unroll
            for (int j = 0; j < 4; ++j)   // scattered 16B/lane from L2-hot W16
                bf[j] = *(const bf16x8*)(wbase + (size_t)j * 16 * H + kt * 32);
            #pragma unroll
            for (int i = 0; i < 4; ++i)
                af[i] = *(const bf16x8*)((const unsigned char*)&As[i * 16 + c][0]
                        + ((((kt * 4 + quad) ^ (c & 7))) << 4));
            __builtin_amdgcn_s_setprio(1);
            #pragma unroll
            for (int i = 0; i < 4; ++i)
                #pragma unroll
                for (int j = 0; j < 4; ++j)
                    acc[i][j] = __builtin_amdgcn_mfma_f32_16x16x32_bf16(af[i], bf[j], acc[i][j], 0, 0, 0);
            __builtin_amdgcn_s_setprio(0);
        }
        if (p < 3) { AWRITE(p + 1); __syncthreads(); }
    }

    // epilogue: esum[i][r] = sum_j v[col]*tanh(u[col]+acc) over this wave's cols
    float esum[4][4];
    #pragma unroll
    for (int i = 0; i < 4; ++i)
        #pragma unroll
        for (int r = 0; r < 4; ++r) esum[i][r] = 0.f;
    #pragma unroll
    for (int j = 0; j < 4; ++j) {
        const int col = wave * 64 + j * 16 + c;
        const float vv = vS[col], uu = uS[col];
        #pragma unroll
        for (int i = 0; i < 4; ++i)
            #pragma unroll
            for (int r = 0; r < 4; ++r)
                esum[i][r] += vv * fast_tanh(uu + acc[i][j][r]);
    }
    // reduce over the 16 c-lanes, stash per-wave partials, cross-wave sum
    #pragma unroll
    for (int i = 0; i < 4; ++i)
        #pragma unroll
        for (int r = 0; r < 4; ++r) {
            float e = esum[i][r];
            e += __shfl_xor(e, 1, 64);
            e += __shfl_xor(e, 2, 64);
            e += __shfl_xor(e, 4, 64);
            e += __shfl_xor(e, 8, 64);
            if (c == 0) red[wave][i * 16 + quad * 4 + r] = e;
        }
    __syncthreads();
    if (tid < 64) {
        float s = 0.f;
        #pragma unroll
        for (int w = 0; w < 8; ++w) s += red[w][tid];
        energy[b * S + s0 + tid] = s;
    }
#undef ALOAD
#undef AWRITE
}

__global__ void softmax_kernel(const float* __restrict__ energy, float* __restrict__ attn) {
    int b = blockIdx.x;
    int t = threadIdx.x;              // 256
    const float* e = energy + b * S;
    float v[8];
    float m = -1e30f;
    #pragma unroll
    for (int i = 0; i < 8; ++i) { v[i] = e[t + i * 256]; m = fmaxf(m, v[i]); }
    #pragma unroll
    for (int off = 1; off < 64; off <<= 1) m = fmaxf(m, __shfl_xor(m, off, 64));
    __shared__ float redm[4], reds[4];
    if ((t & 63) == 0) redm[t >> 6] = m;
    __syncthreads();
    m = fmaxf(fmaxf(redm[0], redm[1]), fmaxf(redm[2], redm[3]));
    float s = 0.f;
    #pragma unroll
    for (int i = 0; i < 8; ++i) { v[i] = __expf(v[i] - m); s += v[i]; }
    #pragma unroll
    for (int off = 1; off < 64; off <<= 1) s += __shfl_xor(s, off, 64);
    if ((t & 63) == 0) reds[t >> 6] = s;
    __syncthreads();
    float inv = 1.0f / (reds[0] + reds[1] + reds[2] + reds[3]);
    #pragma unroll
    for (int i = 0; i < 8; ++i) attn[b * S + t + i * 256] = v[i] * inv;
}

// context: float4 loads (16B/lane), 2 s-groups x 128 h-lanes, LDS combine,
// then one atomicAdd set per block (16 blocks per b).
#define CCH 128
__global__ __launch_bounds__(256) void context_kernel(
        const float* __restrict__ enc, const float* __restrict__ attn,
        float* __restrict__ ctx) {
    const int b  = blockIdx.x >> 4;
    const int ch = blockIdx.x & 15;
    const int t  = threadIdx.x;          // 256
    const int grp = t >> 7;              // 0/1: s-half
    const int ln  = t & 127;             // h-lane (float4)
    __shared__ float aS[CCH];
    __shared__ float red[H];
    if (t < CCH) aS[t] = attn[b * S + ch * CCH + t];
    __syncthreads();
    const float* ebase = enc + ((size_t)(b * S + ch * CCH) + grp * 64) * H + ln * 4;
    float4 acc = make_float4(0.f, 0.f, 0.f, 0.f);
    #pragma unroll 8
    for (int s = 0; s < 64; ++s) {
        const float a = aS[grp * 64 + s];
        const float4 e = *(const float4*)(ebase + (size_t)s * H);
        acc.x += a * e.x; acc.y += a * e.y; acc.z += a * e.z; acc.w += a * e.w;
    }
    if (grp == 0) *(float4*)&red[ln * 4] = acc;
    __syncthreads();
    if (grp == 1) {
        const float4 r = *(const float4*)&red[ln * 4];
        atomicAdd(&ctx[b * H + ln * 4 + 0], acc.x + r.x);
        atomicAdd(&ctx[b * H + ln * 4 + 1], acc.y + r.y);
        atomicAdd(&ctx[b * H + ln * 4 + 2], acc.z + r.z);
        atomicAdd(&ctx[b * H + ln * 4 + 3], acc.w + r.w);
    }
}

extern "C" void kernel_launch(void* const* d_in, const int* in_sizes, int n_in,
                              void* d_out, int out_size, void* d_ws, size_t ws_size,
                              hipStream_t stream) {
    (void)in_sizes; (void)n_in; (void)out_size; (void)ws_size;
    const float* hid = (const float*)d_in[0];
    const float* enc = (const float*)d_in[1];
    const float* Uw  = (const float*)d_in[2];
    const float* Ub  = (const float*)d_in[3];
    const float* Ww  = (const float*)d_in[4];
    const float* Wb  = (const float*)d_in[5];
    const float* Vw  = (const float*)d_in[6];
    // V_b unused: softmax shift-invariant, energy not an output.

    float* out_ctx  = (float*)d_out;          // 64*512
    float* out_attn = out_ctx + B * H;        // 64*2048
    float* energy   = (float*)d_ws;           // 64*2048 fp32
    float* u        = energy + B * S;         // 64*512 fp32
    unsigned short* w16 = (unsigned short*)(u + B * H);   // 512*512 bf16

    hipMemsetAsync(d_out, 0, (size_t)B * H * sizeof(float), stream);   // ctx accum target

    w16_kernel<<<dim3(H * H / (256 * 8)), 256, 0, stream>>>(Ww, w16);
    u_kernel<<<dim3(H / 4, B), 256, 0, stream>>>(hid, Uw, Ub, Wb, u);
    energy_kernel<<<dim3(S / 64, B), 512, 0, stream>>>(enc, w16, Vw, u, energy);
    softmax_kernel<<<B, 256, 0, stream>>>(energy, out_attn);
    context_kernel<<<B * 16, 256, 0, stream>>>(enc, out_attn, out_ctx);
}

// Round 6
// 477.993 us; speedup vs baseline: 1.1725x; 1.0475x over previous
//
#include <hip/hip_runtime.h>
#include <hip/hip_bf16.h>

#define H 512
#define B 64
#define S 2048

typedef __bf16 bf16x8 __attribute__((ext_vector_type(8)));
typedef float f32x4 __attribute__((ext_vector_type(4)));

// pack two fp32 -> two bf16 (RNE) in one uint (low = x)
__device__ __forceinline__ unsigned cvt2(float x, float y) {
    union { __hip_bfloat162 h; unsigned u; } cv;
    cv.h = __float22bfloat162_rn(make_float2(x, y));
    return cv.u;
}

__device__ __forceinline__ float fast_tanh(float x) {
    float e = __expf(2.0f * x);
    float r = __builtin_amdgcn_rcpf(e + 1.0f);
    return 1.0f - 2.0f * r;
}

// ---------------------------------------------------------------------------
// W_w fp32 -> bf16, PRE-PACKED INTO MFMA B-FRAGMENT ORDER.
// Layout: for col-tile ct (16 cols), k-step kt (32 h), lane l = quad*16+c:
//   wpack[((ct*16+kt) << 9) + l*8 .. +7] = W_w[ct*16+c][kt*32+quad*8 .. +7]
// so the energy kernel's B-fragment load is ONE COALESCED 1KB/wave read
// (8 cache lines) instead of a 64-line gather — that gather was the round-5
// bottleneck (L1 transaction-rate bound, ~67M cache-line transactions).
// ---------------------------------------------------------------------------
__global__ __launch_bounds__(256) void wpack_kernel(const float* __restrict__ Ww,
                                                    unsigned short* __restrict__ wp) {
    const int t = blockIdx.x * 256 + threadIdx.x;   // 0..32767
    const int c    = t & 15;
    const int quad = (t >> 4) & 3;
    const int kt   = (t >> 6) & 15;
    const int ct   = t >> 10;
    const float* src = Ww + (size_t)(ct * 16 + c) * H + kt * 32 + quad * 8;
    float4 a = *(const float4*)(src);
    float4 b = *(const float4*)(src + 4);
    uint4 p;
    p.x = cvt2(a.x, a.y); p.y = cvt2(a.z, a.w);
    p.z = cvt2(b.x, b.y); p.w = cvt2(b.z, b.w);
    *(uint4*)(wp + (size_t)t * 8) = p;              // writes fully coalesced
}

// u[b,k] = U_b[k] + W_b[k] + sum_h U_w[k,h] * hid[b,h]
__global__ __launch_bounds__(256) void u_kernel(
        const float* __restrict__ hid, const float* __restrict__ Uw,
        const float* __restrict__ Ub, const float* __restrict__ Wb,
        float* __restrict__ u) {
    const int b = blockIdx.y;
    const int k = blockIdx.x * 4 + (threadIdx.x >> 6);
    const int lane = threadIdx.x & 63;
    const float4* wrow = (const float4*)(Uw + (size_t)k * H);
    const float4* hrow = (const float4*)(hid + (size_t)b * H);
    float4 w0 = wrow[lane * 2], w1 = wrow[lane * 2 + 1];
    float4 h0 = hrow[lane * 2], h1 = hrow[lane * 2 + 1];
    float acc = w0.x * h0.x + w0.y * h0.y + w0.z * h0.z + w0.w * h0.w
              + w1.x * h1.x + w1.y * h1.y + w1.z * h1.z + w1.w * h1.w;
    #pragma unroll
    for (int off = 1; off < 64; off <<= 1) acc += __shfl_xor(acc, off, 64);
    if (lane == 0) u[b * H + k] = acc + Ub[k] + Wb[k];
}

// ---------------------------------------------------------------------------
// energy: BM=64, 512 thr / 8 waves, wave owns 64x64 output (4x4 frags).
// A = enc[64][512] bf16 in LDS, loaded from HBM EXACTLY ONCE per block,
// staged in 4 software-pipelined phases (load slice p+1 || compute slice p).
// B = wpack (fragment-ordered, 512 KB, L2-hot): per kt-step each wave does
// 4 coalesced 1KB loads directly into bf16x8 fragments — no LDS for B.
// A chunk-XOR swizzle: 16B chunk index ^= (row&7), write + read side.
// ---------------------------------------------------------------------------
__global__ __launch_bounds__(512, 4) void energy_kernel(
        const float* __restrict__ enc, const unsigned short* __restrict__ wpack,
        const float* __restrict__ Vw, const float* __restrict__ u,
        float* __restrict__ energy) {
    const int s0  = blockIdx.x * 64;
    const int b   = blockIdx.y;
    const int tid = threadIdx.x;          // 0..511
    const int wave = tid >> 6, lane = tid & 63;
    const int quad = lane >> 4, c = lane & 15;

    __shared__ unsigned short As[64][512];    // 64 KB, chunk-swizzled
    __shared__ float uS[H], vS[H];            // 4 KB
    __shared__ float red[8][64];              // 2 KB

    // A staging: thread owns row (tid>>3), 16 floats per phase at (tid&7)*16
    const int arow = tid >> 3;
    const int a8   = tid & 7;
    const int akey = arow & 7;
    const float* pa = enc + ((size_t)(b * S + s0 + arow)) * H + a8 * 16;
    unsigned char* arowbase = (unsigned char*)&As[arow][0];

    float4 av0, av1, av2, av3;
#define ALOAD(p) { const float4* q_ = (const float4*)(pa + (p) * 128);         \
    av0 = q_[0]; av1 = q_[1]; av2 = q_[2]; av3 = q_[3]; }
#define AWRITE(p) { uint4 lo_, hi_;                                            \
    lo_.x = cvt2(av0.x, av0.y); lo_.y = cvt2(av0.z, av0.w);                    \
    lo_.z = cvt2(av1.x, av1.y); lo_.w = cvt2(av1.z, av1.w);                    \
    hi_.x = cvt2(av2.x, av2.y); hi_.y = cvt2(av2.z, av2.w);                    \
    hi_.z = cvt2(av3.x, av3.y); hi_.w = cvt2(av3.z, av3.w);                    \
    const int ci_ = (p) * 16 + a8 * 2;                                         \
    *(uint4*)(arowbase + (((ci_)     ^ akey) << 4)) = lo_;                     \
    *(uint4*)(arowbase + (((ci_ + 1) ^ akey) << 4)) = hi_; }

    ALOAD(0);
    uS[tid] = u[b * H + tid];
    vS[tid] = Vw[tid];
    AWRITE(0);
    __syncthreads();

    const f32x4 fzero = {0.f, 0.f, 0.f, 0.f};
    f32x4 acc[4][4];
    #pragma unroll
    for (int i = 0; i < 4; ++i)
        #pragma unroll
        for (int j = 0; j < 4; ++j) acc[i][j] = fzero;

    // per-lane B base inside the fragment-packed W: lane's 16B slot
    const unsigned short* wl = wpack + lane * 8;

    #pragma unroll
    for (int p = 0; p < 4; ++p) {
        if (p < 3) ALOAD(p + 1);          // next A slice flies under MFMA
        #pragma unroll
        for (int k2 = 0; k2 < 4; ++k2) {
            const int kt = p * 4 + k2;
            bf16x8 bf[4], af[4];
            #pragma unroll
            for (int j = 0; j < 4; ++j)   // coalesced 1KB/wave from L2-hot wpack
                bf[j] = *(const bf16x8*)(wl + (((wave * 4 + j) * 16 + kt) << 9));
            #pragma unroll
            for (int i = 0; i < 4; ++i)
                af[i] = *(const bf16x8*)((const unsigned char*)&As[i * 16 + c][0]
                        + ((((kt * 4 + quad) ^ (c & 7))) << 4));
            __builtin_amdgcn_s_setprio(1);
            #pragma unroll
            for (int i = 0; i < 4; ++i)
                #pragma unroll
                for (int j = 0; j < 4; ++j)
                    acc[i][j] = __builtin_amdgcn_mfma_f32_16x16x32_bf16(af[i], bf[j], acc[i][j], 0, 0, 0);
            __builtin_amdgcn_s_setprio(0);
        }
        if (p < 3) { AWRITE(p + 1); __syncthreads(); }
    }

    // epilogue: esum[i][r] = sum_j v[col]*tanh(u[col]+acc) over this wave's cols
    float esum[4][4];
    #pragma unroll
    for (int i = 0; i < 4; ++i)
        #pragma unroll
        for (int r = 0; r < 4; ++r) esum[i][r] = 0.f;
    #pragma unroll
    for (int j = 0; j < 4; ++j) {
        const int col = wave * 64 + j * 16 + c;
        const float vv = vS[col], uu = uS[col];
        #pragma unroll
        for (int i = 0; i < 4; ++i)
            #pragma unroll
            for (int r = 0; r < 4; ++r)
                esum[i][r] += vv * fast_tanh(uu + acc[i][j][r]);
    }
    // reduce over the 16 c-lanes, stash per-wave partials, cross-wave sum
    #pragma unroll
    for (int i = 0; i < 4; ++i)
        #pragma unroll
        for (int r = 0; r < 4; ++r) {
            float e = esum[i][r];
            e += __shfl_xor(e, 1, 64);
            e += __shfl_xor(e, 2, 64);
            e += __shfl_xor(e, 4, 64);
            e += __shfl_xor(e, 8, 64);
            if (c == 0) red[wave][i * 16 + quad * 4 + r] = e;
        }
    __syncthreads();
    if (tid < 64) {
        float s = 0.f;
        #pragma unroll
        for (int w = 0; w < 8; ++w) s += red[w][tid];
        energy[b * S + s0 + tid] = s;
    }
#undef ALOAD
#undef AWRITE
}

__global__ void softmax_kernel(const float* __restrict__ energy, float* __restrict__ attn) {
    int b = blockIdx.x;
    int t = threadIdx.x;              // 256
    const float* e = energy + b * S;
    float v[8];
    float m = -1e30f;
    #pragma unroll
    for (int i = 0; i < 8; ++i) { v[i] = e[t + i * 256]; m = fmaxf(m, v[i]); }
    #pragma unroll
    for (int off = 1; off < 64; off <<= 1) m = fmaxf(m, __shfl_xor(m, off, 64));
    __shared__ float redm[4], reds[4];
    if ((t & 63) == 0) redm[t >> 6] = m;
    __syncthreads();
    m = fmaxf(fmaxf(redm[0], redm[1]), fmaxf(redm[2], redm[3]));
    float s = 0.f;
    #pragma unroll
    for (int i = 0; i < 8; ++i) { v[i] = __expf(v[i] - m); s += v[i]; }
    #pragma unroll
    for (int off = 1; off < 64; off <<= 1) s += __shfl_xor(s, off, 64);
    if ((t & 63) == 0) reds[t >> 6] = s;
    __syncthreads();
    float inv = 1.0f / (reds[0] + reds[1] + reds[2] + reds[3]);
    #pragma unroll
    for (int i = 0; i < 8; ++i) attn[b * S + t + i * 256] = v[i] * inv;
}

// context: float4 loads (16B/lane), 2 s-groups x 128 h-lanes, LDS combine,
// then one atomicAdd set per block (16 blocks per b).
#define CCH 128
__global__ __launch_bounds__(256) void context_kernel(
        const float* __restrict__ enc, const float* __restrict__ attn,
        float* __restrict__ ctx) {
    const int b  = blockIdx.x >> 4;
    const int ch = blockIdx.x & 15;
    const int t  = threadIdx.x;          // 256
    const int grp = t >> 7;              // 0/1: s-half
    const int ln  = t & 127;             // h-lane (float4)
    __shared__ float aS[CCH];
    __shared__ float red[H];
    if (t < CCH) aS[t] = attn[b * S + ch * CCH + t];
    __syncthreads();
    const float* ebase = enc + ((size_t)(b * S + ch * CCH) + grp * 64) * H + ln * 4;
    float4 acc = make_float4(0.f, 0.f, 0.f, 0.f);
    #pragma unroll 8
    for (int s = 0; s < 64; ++s) {
        const float a = aS[grp * 64 + s];
        const float4 e = *(const float4*)(ebase + (size_t)s * H);
        acc.x += a * e.x; acc.y += a * e.y; acc.z += a * e.z; acc.w += a * e.w;
    }
    if (grp == 0) *(float4*)&red[ln * 4] = acc;
    __syncthreads();
    if (grp == 1) {
        const float4 r = *(const float4*)&red[ln * 4];
        atomicAdd(&ctx[b * H + ln * 4 + 0], acc.x + r.x);
        atomicAdd(&ctx[b * H + ln * 4 + 1], acc.y + r.y);
        atomicAdd(&ctx[b * H + ln * 4 + 2], acc.z + r.z);
        atomicAdd(&ctx[b * H + ln * 4 + 3], acc.w + r.w);
    }
}

extern "C" void kernel_launch(void* const* d_in, const int* in_sizes, int n_in,
                              void* d_out, int out_size, void* d_ws, size_t ws_size,
                              hipStream_t stream) {
    (void)in_sizes; (void)n_in; (void)out_size; (void)ws_size;
    const float* hid = (const float*)d_in[0];
    const float* enc = (const float*)d_in[1];
    const float* Uw  = (const float*)d_in[2];
    const float* Ub  = (const float*)d_in[3];
    const float* Ww  = (const float*)d_in[4];
    const float* Wb  = (const float*)d_in[5];
    const float* Vw  = (const float*)d_in[6];
    // V_b unused: softmax shift-invariant, energy not an output.

    float* out_ctx  = (float*)d_out;          // 64*512
    float* out_attn = out_ctx + B * H;        // 64*2048
    float* energy   = (float*)d_ws;           // 64*2048 fp32
    float* u        = energy + B * S;         // 64*512 fp32
    unsigned short* wpack = (unsigned short*)(u + B * H);   // 512*512 bf16, fragment-packed

    hipMemsetAsync(d_out, 0, (size_t)B * H * sizeof(float), stream);   // ctx accum target

    wpack_kernel<<<dim3(H * H / (256 * 8)), 256, 0, stream>>>(Ww, wpack);
    u_kernel<<<dim3(H / 4, B), 256, 0, stream>>>(hid, Uw, Ub, Wb, u);
    energy_kernel<<<dim3(S / 64, B), 512, 0, stream>>>(enc, wpack, Vw, u, energy);
    softmax_kernel<<<B, 256, 0, stream>>>(energy, out_attn);
    context_kernel<<<B * 16, 256, 0, stream>>>(enc, out_attn, out_ctx);
}